// Round 3
// baseline (696.614 us; speedup 1.0000x reference)
//
#include <hip/hip_runtime.h>
#include <math.h>

#define CCH 32              // channels per row
#define QPR 8               // f4 quads per row (32 ch / 4 floats)
#define CAP 512             // sids owned per block
#define PCH 32              // LDS table row stride (uints) — unpadded: table is linear
#define RPT 8               // consecutive rows per thread (≈ mean run length)
#define CHUNK 256           // rows per block-iteration (32 row-slots x RPT)
#define ENC_NEGINF 0x007FFFFFu

typedef float f4 __attribute__((ext_vector_type(4)));
typedef unsigned u32;
typedef u32 u32x4 __attribute__((ext_vector_type(4)));

// Monotonic bijection float -> uint: a < b  <=>  encf(a) < encf(b) (unsigned).
// atomicMax over encodings == exact float max (bit-exact, no arithmetic).
__device__ __forceinline__ u32 encf(float x) {
    u32 b = __float_as_uint(x);
    return (b & 0x80000000u) ? ~b : (b | 0x80000000u);
}
// Decode; untouched entries (empty sid) -> +0.0f bits (reference isinf->0 rule).
__device__ __forceinline__ u32 decbits(u32 u) {
    if (u == ENC_NEGINF) return 0u;
    return (u & 0x80000000u) ? (u ^ 0x80000000u) : ~u;
}

__device__ __forceinline__ f4 f4max(f4 a, f4 b) {
    f4 r;
    r.x = fmaxf(a.x, b.x);
    r.y = fmaxf(a.y, b.y);
    r.z = fmaxf(a.z, b.z);
    r.w = fmaxf(a.w, b.w);
    return r;
}

__device__ __forceinline__ void flush(u32* __restrict__ tab, int sidl, int c0,
                                      f4 acc) {
    u32* t = tab + sidl * PCH + c0;
    atomicMax(t + 0, encf(acc.x));
    atomicMax(t + 1, encf(acc.y));
    atomicMax(t + 2, encf(acc.z));
    atomicMax(t + 3, encf(acc.w));
}

// K0: startc[j] = lower_bound(ids, j*CAP) for j in [0, NB].
__global__ void bounds_kernel(const int* __restrict__ ids,
                              int* __restrict__ startc,
                              int N, int NB) {
    int j = blockIdx.x * blockDim.x + threadIdx.x;
    if (j > NB) return;
    int target = j * CAP;
    int lo = 0, hi = N;
    while (lo < hi) {
        int mid = (lo + hi) >> 1;
        if (ids[mid] < target) lo = mid + 1;
        else hi = mid;
    }
    startc[j] = lo;
}

// K1: block b owns sids [b*CAP,(b+1)*CAP) and rows [startc[b], startc[b+1]).
// 64 KB LDS table -> exactly 2 blocks/CU, grid 977 -> 95% tail efficiency
// (vs 76% at CAP=256). Each thread merges RPT consecutive rows in registers
// (sorted ids); LDS atomicMax only at run boundaries (proven cost-invisible).
// Branchless clamped loop: out-of-range rows clamp to the last valid row —
// idempotent duplicate max, L1-hit loads, no divergent tail path.
__global__ __launch_bounds__(256) void pool_kernel(
    const f4* __restrict__ feat, const int* __restrict__ ids,
    const int* __restrict__ startc, u32* __restrict__ out,
    int M) {
    __shared__ u32 tab[CAP * PCH];
    u32x4* tab4 = (u32x4*)tab;
    const int b    = blockIdx.x;
    const int sid0 = b * CAP;
    const int rs   = startc[b];
    const int re   = startc[b + 1];
    const int tid  = threadIdx.x;
    const int q    = tid & (QPR - 1);   // quad (4 channels) within row
    const int rofs = tid >> 3;          // row slot 0..31
    const int c0   = q * 4;

    const u32x4 ninf4 = {ENC_NEGINF, ENC_NEGINF, ENC_NEGINF, ENC_NEGINF};
    for (int i = tid; i < CAP * PCH / 4; i += 256) tab4[i] = ninf4;
    __syncthreads();

    if (re > rs) {
        const int rmax = re - 1;
        for (int cbase = rs; cbase < re; cbase += CHUNK) {
            const int r0 = cbase + rofs * RPT;
            f4  v[RPT];
            int s[RPT];
            // Issue all 16 independent loads before any use; clamp keeps the
            // loop uniform (duplicates of the last row are idempotent).
            #pragma unroll
            for (int k = 0; k < RPT; ++k) {
                int rc = r0 + k; rc = rc < rmax ? rc : rmax;
                v[k] = feat[(size_t)rc * QPR + q];
            }
            #pragma unroll
            for (int k = 0; k < RPT; ++k) {
                int rc = r0 + k; rc = rc < rmax ? rc : rmax;
                s[k] = ids[rc];
            }

            f4  acc = v[0];
            int cs  = s[0];
            #pragma unroll
            for (int k = 1; k < RPT; ++k) {
                if (s[k] == cs) {
                    acc = f4max(acc, v[k]);
                } else {
                    flush(tab, cs - sid0, c0, acc);
                    acc = v[k];
                    cs  = s[k];
                }
            }
            flush(tab, cs - sid0, c0, acc);
        }
    }
    __syncthreads();

    // Flush table -> out. PCH=32 makes the table linear: uint4 all the way,
    // 16 B/lane coalesced. Empty sids decode to +0.0f.
    int nsid = M - sid0; if (nsid > CAP) nsid = CAP;
    u32x4* ob = (u32x4*)(out + (size_t)sid0 * CCH);
    for (int i = tid; i < nsid * QPR; i += 256) {
        u32x4 t = tab4[i];
        u32x4 d;
        d.x = decbits(t.x);
        d.y = decbits(t.y);
        d.z = decbits(t.z);
        d.w = decbits(t.w);
        ob[i] = d;
    }
}

extern "C" void kernel_launch(void* const* d_in, const int* in_sizes, int n_in,
                              void* d_out, int out_size, void* d_ws, size_t ws_size,
                              hipStream_t stream) {
    const f4*  feat = (const f4*)d_in[0];
    const int* ids  = (const int*)d_in[1];

    const int N  = in_sizes[0] / CCH;        // 4,000,000
    const int M  = out_size / CCH;           // 500,000
    const int NB = (M + CAP - 1) / CAP;      // 977

    int* startc = (int*)d_ws;                // (NB+1) ints

    int gridA = (NB + 1 + 255) / 256;
    bounds_kernel<<<gridA, 256, 0, stream>>>(ids, startc, N, NB);
    pool_kernel<<<NB, 256, 0, stream>>>(feat, ids, startc,
                                        (u32*)d_out, M);
}